// Round 5
// baseline (676.840 us; speedup 1.0000x reference)
//
#include <hip/hip_runtime.h>

typedef unsigned short u16;
typedef __attribute__((ext_vector_type(8))) short short8;     // 8 bf16 (4 VGPRs)
typedef __attribute__((ext_vector_type(4))) float floatx4;    // 4 fp32 acc

#define B_ 4
#define T_ 2048
#define CH 64

__device__ __forceinline__ u16 f2bf(float f) {
  unsigned int x = __float_as_uint(f);
  return (u16)((x + 0x7FFFu + ((x >> 16) & 1u)) >> 16);
}
__device__ __forceinline__ float bf2f(u16 u) {
  union { unsigned int i; float f; } v; v.i = ((unsigned int)u) << 16; return v.f;
}

// lgkm-only barrier: all cross-wave hazards in chain_kernel are LDS (Sb/rhsT/uT).
__device__ __forceinline__ void barrier_lgkm() {
  asm volatile("s_waitcnt lgkmcnt(0)\n\ts_barrier" ::: "memory");
}

// Opaque asm loads: compiler cannot sink/duplicate/rematerialize these, so
// issue points and the hand-counted vmcnt ledger are exact.
#define GL(dst, addr, IMM) \
  asm volatile("global_load_dwordx4 %0, %1, off offset:" #IMM : "=v"(dst) : "v"(addr))
#define GLU(dst, addr, IMM) \
  asm volatile("global_load_ushort %0, %1, off offset:" #IMM : "=v"(dst) : "v"(addr))
#define GS(addr, val, IMM) \
  asm volatile("global_store_short %0, %1, off offset:" #IMM :: "v"(addr), "v"(val))

#define GLA(slot, base, I0, I1, I2, I3) do { \
  GL(af[slot][0], base, I0); GL(af[slot][1], base, I1); \
  GL(af[slot][2], base, I2); GL(af[slot][3], base, I3); } while (0)

#define GLKT(nt0) do { \
  const u16* kp0_ = ktb + (size_t)(nt0) * ktstep; \
  GL(ktf[nt0][0], kp0_, 0); GL(ktf[nt0][1], kp0_, 64); \
  const u16* kp1_ = ktb + (size_t)(nt0 + 1) * ktstep; \
  GL(ktf[nt0 + 1][0], kp1_, 0); GL(ktf[nt0 + 1][1], kp1_, 64); } while (0)

#define GLWM do { \
  GL(wpf0, wrow, 0); GL(wpf1, wrow, 64); \
  GL(mnf0, mnrow, 0); GL(mnf1, mnrow, 64); } while (0)

#define GLVV do { \
  GLU(vv0, vvb, 0); GLU(vv1, vvb, 2048); \
  GLU(vv2, vvb2, 0); GLU(vv3, vvb2, 2048); } while (0)

#define NOOP ((void)0);

// One A-early iteration. Counted vmcnt (never 0); sched_barrier(0x387) keeps
// MFMAs below the wait (MFMA=0x8 excluded) while DS/VALU may flow.
// Ledger (identical both roles; Q-wave o-stores retire together with vv at i1):
//  it0 w4 | it1..it6 w8 | it7 w4 ; i1: issue af0/af1(next) then w8.
#define A_IT(K, NW, EXTRA) do { \
  asm volatile("s_waitcnt vmcnt(" #NW ")"); \
  __builtin_amdgcn_sched_barrier(0x387); \
  EXTRA \
  short8 b0_ = *reinterpret_cast<const short8*>(sbRow + (K * 4 + 0) * 32 + quad * 8); \
  short8 b1_ = *reinterpret_cast<const short8*>(sbRow + (K * 4 + 1) * 32 + quad * 8); \
  short8 b2_ = *reinterpret_cast<const short8*>(sbRow + (K * 4 + 2) * 32 + quad * 8); \
  short8 b3_ = *reinterpret_cast<const short8*>(sbRow + (K * 4 + 3) * 32 + quad * 8); \
  ac0 = __builtin_amdgcn_mfma_f32_16x16x32_bf16(af[K][0], b0_, ac0, 0, 0, 0); \
  ac1 = __builtin_amdgcn_mfma_f32_16x16x32_bf16(af[K][1], b1_, ac1, 0, 0, 0); \
  ac2 = __builtin_amdgcn_mfma_f32_16x16x32_bf16(af[K][2], b2_, ac2, 0, 0, 0); \
  ac3 = __builtin_amdgcn_mfma_f32_16x16x32_bf16(af[K][3], b3_, ac3, 0, 0, 0); \
} while (0)

// Pointer set for the chunk whose A-early/prefetch this interval serves.
#define SETPTRS(N) \
  const int nxc_ = (N); \
  const u16* aqN = Abase + (size_t)(b * tgs + nxc_ * CH + m0 + l16) * 1024 + quad * 8; \
  const u16* ktb = KT + ((size_t)b * 1024 + d0w + l16) * tgs + (size_t)nxc_ * CH + quad * 8; \
  const size_t pwN = ((size_t)(nxc_ * B_ + b) * CH) * 64; \
  const u16* wrow  = WPbase + pwN + (size_t)(m0 + l16) * 64 + quad * 8; \
  const u16* mnrow = MNbase + pwN + (size_t)(m0 + l16) * 64 + quad * 8; \
  const u16* vvb  = Vbf + (size_t)(b * tgs + nxc_ * CH + m0 + quad * 4) * 1024 + c0 + l16; \
  const u16* vvb2 = vvb + 2048;

// i1 (corr + rhs) and i2 (u) for chunk C. Issues af0/af1 for chunk C+1's
// A-early before the wait so the wait count is role-uniform.
#define I1I2(C) do { \
  const int nn_ = ((C) + 1 < cpg) ? ((C) + 1) : (cpg - 1); \
  const u16* aq2_ = Abase + (size_t)(b * tgs + nn_ * CH + m0 + l16) * 1024 + quad * 8; \
  GLA(0, aq2_, 0, 64, 128, 192); \
  GLA(1, aq2_, 256, 320, 384, 448); \
  asm volatile("s_waitcnt vmcnt(8)"); \
  __builtin_amdgcn_sched_barrier(0); \
  accS = (ac0 + ac1) + (ac2 + ac3); \
  { \
    short8 cu0_ = *reinterpret_cast<const short8*>(&uT[l16][quad * 8]); \
    short8 cu1_ = *reinterpret_cast<const short8*>(&uT[l16][32 + quad * 8]); \
    accS = __builtin_amdgcn_mfma_f32_16x16x32_bf16(mnf0, cu0_, accS, 0, 0, 0); \
    accS = __builtin_amdgcn_mfma_f32_16x16x32_bf16(mnf1, cu1_, accS, 0, 0, 0); \
  } \
  if (isK) { \
    rhsT[l16][m0 + quad * 4 + 0] = f2bf(bf2f((u16)vv0) - accS[0]); \
    rhsT[l16][m0 + quad * 4 + 1] = f2bf(bf2f((u16)vv1) - accS[1]); \
    rhsT[l16][m0 + quad * 4 + 2] = f2bf(bf2f((u16)vv2) - accS[2]); \
    rhsT[l16][m0 + quad * 4 + 3] = f2bf(bf2f((u16)vv3) - accS[3]); \
  } \
  barrier_lgkm(); \
  if (isK) { \
    floatx4 uacc = {}; \
    short8 br0_ = *reinterpret_cast<const short8*>(&rhsT[l16][quad * 8]); \
    short8 br1_ = *reinterpret_cast<const short8*>(&rhsT[l16][32 + quad * 8]); \
    uacc = __builtin_amdgcn_mfma_f32_16x16x32_bf16(wpf0, br0_, uacc, 0, 0, 0); \
    uacc = __builtin_amdgcn_mfma_f32_16x16x32_bf16(wpf1, br1_, uacc, 0, 0, 0); \
    uT[l16][m0 + quad * 4 + 0] = f2bf(uacc[0]); \
    uT[l16][m0 + quad * 4 + 1] = f2bf(uacc[1]); \
    uT[l16][m0 + quad * 4 + 2] = f2bf(uacc[2]); \
    uT[l16][m0 + quad * 4 + 3] = f2bf(uacc[3]); \
  } \
  barrier_lgkm(); \
} while (0)

// ---------------------------------------------------------------------------
// x fp32 -> bf16 (full tensor). grid (B_*T_), 256 thr x 4 elems.
// ---------------------------------------------------------------------------
__global__ __launch_bounds__(256) void xconv_kernel(const float* __restrict__ x,
                                                    u16* __restrict__ Xbf) {
  size_t idx = ((size_t)blockIdx.x * 256 + threadIdx.x) * 4;
  float4 v = *reinterpret_cast<const float4*>(&x[idx]);
  ushort4 o;
  o.x = f2bf(v.x); o.y = f2bf(v.y); o.z = f2bf(v.z); o.w = f2bf(v.w);
  *reinterpret_cast<ushort4*>(&Xbf[idx]) = o;
}

// ---------------------------------------------------------------------------
// Weight transpose+convert: T[n][k] = bf16(W[k][n]). grid (16,16,4).
// ---------------------------------------------------------------------------
__global__ __launch_bounds__(256) void wtrans_kernel(
    const float* __restrict__ W0, const float* __restrict__ W1,
    const float* __restrict__ W2, const float* __restrict__ W3,
    u16* __restrict__ T0, u16* __restrict__ T1,
    u16* __restrict__ T2, u16* __restrict__ T3)
{
  const int z = blockIdx.z;
  const float* W = (z == 0) ? W0 : (z == 1) ? W1 : (z == 2) ? W2 : W3;
  u16* T = (z == 0) ? T0 : (z == 1) ? T1 : (z == 2) ? T2 : T3;
  const int k0 = blockIdx.x * 64, n0 = blockIdx.y * 64;
  const int tid = threadIdx.x;
  __shared__ float Tile[64][65];
#pragma unroll
  for (int i = 0; i < 4; ++i) {
    int lin = tid + i * 256;
    int r = lin >> 4, c4 = (lin & 15) * 4;
    *reinterpret_cast<float4*>(&Tile[r][c4]) =
        *reinterpret_cast<const float4*>(&W[(size_t)(k0 + r) * 1024 + n0 + c4]);
  }
  __syncthreads();
#pragma unroll
  for (int i = 0; i < 4; ++i) {
    int lin = tid + i * 256;
    int r = lin >> 4, c4 = (lin & 15) * 4;   // r: n-within, c4: k-within
    ushort4 o;
    o.x = f2bf(Tile[c4 + 0][r]); o.y = f2bf(Tile[c4 + 1][r]);
    o.z = f2bf(Tile[c4 + 2][r]); o.w = f2bf(Tile[c4 + 3][r]);
    *reinterpret_cast<ushort4*>(&T[(size_t)(n0 + r) * 1024 + k0 + c4]) = o;
  }
}

// ---------------------------------------------------------------------------
// MFMA GEMM for QKV. 128x128 tile, 4 waves (2x2), 4x4 of 16x16x32, BK=32.
// grid (rows/128, 8, 3).
// ---------------------------------------------------------------------------
__global__ __launch_bounds__(256) void mgemm_qkv(
    const u16* __restrict__ Xbf,
    const u16* __restrict__ WqT, const u16* __restrict__ WkT, const u16* __restrict__ WvT,
    u16* __restrict__ Qbf, u16* __restrict__ Kbf, u16* __restrict__ Vbf,
    int tg, int lsh)
{
  const int z = blockIdx.z;
  const u16* BT = (z == 0) ? WqT : ((z == 1) ? WkT : WvT);
  u16* O = (z == 0) ? Qbf : ((z == 1) ? Kbf : Vbf);
  const float scale = (z == 0) ? 0.03125f : 1.0f;
  const int r0 = blockIdx.x * 128, c0 = blockIdx.y * 128;
  const int tid = threadIdx.x;
  const int lane = tid & 63, wave = tid >> 6;
  const int quad = lane >> 4, l16 = lane & 15;
  const int wr = (wave >> 1) * 64, wc = (wave & 1) * 64;

  __shared__ u16 As[128][40];
  __shared__ u16 Bs[128][40];

  const int ar = tid >> 1, ac = (tid & 1) * 16;
  const int lr = r0 + ar;
  const int agrow = ((lr >> lsh) << 11) + tg + (lr & ((1 << lsh) - 1));
  const u16* aptr = &Xbf[(size_t)agrow * 1024 + ac];
  const u16* bptr = &BT[(size_t)(c0 + ar) * 1024 + ac];

  floatx4 acc[4][4] = {};
  for (int k0 = 0; k0 < 1024; k0 += 32) {
    float4 av0 = *reinterpret_cast<const float4*>(aptr + k0);
    float4 av1 = *reinterpret_cast<const float4*>(aptr + k0 + 8);
    float4 bv0 = *reinterpret_cast<const float4*>(bptr + k0);
    float4 bv1 = *reinterpret_cast<const float4*>(bptr + k0 + 8);
    __syncthreads();
    *reinterpret_cast<float4*>(&As[ar][ac]) = av0;
    *reinterpret_cast<float4*>(&As[ar][ac + 8]) = av1;
    *reinterpret_cast<float4*>(&Bs[ar][ac]) = bv0;
    *reinterpret_cast<float4*>(&Bs[ar][ac + 8]) = bv1;
    __syncthreads();
    short8 afr[4], bfr[4];
#pragma unroll
    for (int i = 0; i < 4; ++i) {
      afr[i] = *reinterpret_cast<const short8*>(&As[wr + i * 16 + l16][quad * 8]);
      bfr[i] = *reinterpret_cast<const short8*>(&Bs[wc + i * 16 + l16][quad * 8]);
    }
#pragma unroll
    for (int mi = 0; mi < 4; ++mi)
#pragma unroll
      for (int ni = 0; ni < 4; ++ni)
        acc[mi][ni] = __builtin_amdgcn_mfma_f32_16x16x32_bf16(afr[mi], bfr[ni], acc[mi][ni], 0, 0, 0);
  }
#pragma unroll
  for (int mi = 0; mi < 4; ++mi)
#pragma unroll
    for (int reg = 0; reg < 4; ++reg) {
      int row = r0 + wr + mi * 16 + quad * 4 + reg;
#pragma unroll
      for (int ni = 0; ni < 4; ++ni) {
        int col = c0 + wc + ni * 16 + l16;
        O[(size_t)row * 1024 + col] = f2bf(acc[mi][ni][reg] * scale);
      }
    }
}

// ---------------------------------------------------------------------------
// MFMA GEMM out-proj: fp32 out. grid (rows/128, 8)
// ---------------------------------------------------------------------------
__global__ __launch_bounds__(256) void mgemm_out(
    const u16* __restrict__ Obf, const u16* __restrict__ WoT,
    float* __restrict__ out, int tg, int lsh)
{
  const int r0 = blockIdx.x * 128, c0 = blockIdx.y * 128;
  const int tid = threadIdx.x;
  const int lane = tid & 63, wave = tid >> 6;
  const int quad = lane >> 4, l16 = lane & 15;
  const int wr = (wave >> 1) * 64, wc = (wave & 1) * 64;

  __shared__ u16 As[128][40];
  __shared__ u16 Bs[128][40];

  const int ar = tid >> 1, ac = (tid & 1) * 16;
  const u16* aptr = &Obf[(size_t)(r0 + ar) * 1024 + ac];
  const u16* bptr = &WoT[(size_t)(c0 + ar) * 1024 + ac];

  floatx4 acc[4][4] = {};
  for (int k0 = 0; k0 < 1024; k0 += 32) {
    float4 av0 = *reinterpret_cast<const float4*>(aptr + k0);
    float4 av1 = *reinterpret_cast<const float4*>(aptr + k0 + 8);
    float4 bv0 = *reinterpret_cast<const float4*>(bptr + k0);
    float4 bv1 = *reinterpret_cast<const float4*>(bptr + k0 + 8);
    __syncthreads();
    *reinterpret_cast<float4*>(&As[ar][ac]) = av0;
    *reinterpret_cast<float4*>(&As[ar][ac + 8]) = av1;
    *reinterpret_cast<float4*>(&Bs[ar][ac]) = bv0;
    *reinterpret_cast<float4*>(&Bs[ar][ac + 8]) = bv1;
    __syncthreads();
    short8 afr[4], bfr[4];
#pragma unroll
    for (int i = 0; i < 4; ++i) {
      afr[i] = *reinterpret_cast<const short8*>(&As[wr + i * 16 + l16][quad * 8]);
      bfr[i] = *reinterpret_cast<const short8*>(&Bs[wc + i * 16 + l16][quad * 8]);
    }
#pragma unroll
    for (int mi = 0; mi < 4; ++mi)
#pragma unroll
      for (int ni = 0; ni < 4; ++ni)
        acc[mi][ni] = __builtin_amdgcn_mfma_f32_16x16x32_bf16(afr[mi], bfr[ni], acc[mi][ni], 0, 0, 0);
  }
#pragma unroll
  for (int mi = 0; mi < 4; ++mi)
#pragma unroll
    for (int reg = 0; reg < 4; ++reg) {
      int lr = r0 + wr + mi * 16 + quad * 4 + reg;
      int grow = ((lr >> lsh) << 11) + tg + (lr & ((1 << lsh) - 1));
#pragma unroll
      for (int ni = 0; ni < 4; ++ni) {
        int col = c0 + wc + ni * 16 + l16;
        out[(size_t)grow * 1024 + col] = acc[mi][ni][reg];
      }
    }
}

// ---------------------------------------------------------------------------
// Row-normalize Kbf in place (bf16, fp32 math). grid (rows).
// ---------------------------------------------------------------------------
__global__ __launch_bounds__(256) void knorm_kernel(u16* __restrict__ Kbf) {
  const int row = blockIdx.x;
  const int tid = threadIdx.x;
  ushort4 v4 = *reinterpret_cast<const ushort4*>(&Kbf[(size_t)row * 1024 + tid * 4]);
  float a = bf2f(v4.x), b = bf2f(v4.y), c = bf2f(v4.z), d = bf2f(v4.w);
  float ss = a * a + b * b + c * c + d * d;
#pragma unroll
  for (int off = 32; off > 0; off >>= 1) ss += __shfl_down(ss, off);
  __shared__ float wsum[4];
  if ((tid & 63) == 0) wsum[tid >> 6] = ss;
  __syncthreads();
  float tot = wsum[0] + wsum[1] + wsum[2] + wsum[3];
  float inv = 1.0f / fmaxf(sqrtf(tot), 1e-12f);
  ushort4 o;
  o.x = f2bf(a * inv); o.y = f2bf(b * inv); o.z = f2bf(c * inv); o.w = f2bf(d * inv);
  *reinterpret_cast<ushort4*>(&Kbf[(size_t)row * 1024 + tid * 4]) = o;
}

// ---------------------------------------------------------------------------
// Transpose Kbf -> KT[b][d][t_local] (bf16). grid (tgs/64, 16, B_), 256 thr.
// ---------------------------------------------------------------------------
__global__ __launch_bounds__(256) void ktrans_kernel(const u16* __restrict__ Kbf,
                                                     u16* __restrict__ KT,
                                                     int tgs) {
  const int t0 = blockIdx.x * 64;
  const int d0 = blockIdx.y * 64;
  const int b = blockIdx.z;
  const int tid = threadIdx.x;
  __shared__ u16 Tile[64][68];
#pragma unroll
  for (int i = 0; i < 4; ++i) {
    int lin = tid + i * 256;
    int r = lin >> 4, c4 = (lin & 15) * 4;
    *reinterpret_cast<ushort4*>(&Tile[r][c4]) =
        *reinterpret_cast<const ushort4*>(&Kbf[(size_t)(b * tgs + t0 + r) * 1024 + d0 + c4]);
  }
  __syncthreads();
#pragma unroll
  for (int i = 0; i < 4; ++i) {
    int lin = tid + i * 256;
    int r = lin >> 4, c4 = (lin & 15) * 4;
    ushort4 o;
    o.x = Tile[c4 + 0][r]; o.y = Tile[c4 + 1][r];
    o.z = Tile[c4 + 2][r]; o.w = Tile[c4 + 3][r];
    *reinterpret_cast<ushort4*>(&KT[((size_t)b * 1024 + d0 + r) * tgs + t0 + c4]) = o;
  }
}

// ---------------------------------------------------------------------------
// Per (chunk, batch): MFMA QK^T/KK^T -> P and A -> W=(I+A)^{-1} -> bf16.
// v4: also computes the CROSS-chunk couplings used by chain's recurrence
// pipelining: Mb[cc] = K_cc K_{cc-1}^T, Nb[cc] = Q_cc K_{cc-1}^T (full 64x64,
// zeros for cc==0). grid (cpg, B_), 256 threads.
// ---------------------------------------------------------------------------
__global__ __launch_bounds__(256) void attn_winv_kernel(
    const u16* __restrict__ Qbf, const u16* __restrict__ Kbf,
    u16* __restrict__ Pb, u16* __restrict__ Wb,
    u16* __restrict__ Mb, u16* __restrict__ Nb, int tgs)
{
  const int cc = blockIdx.x;
  const int b = blockIdx.y;
  const int base = b * tgs + cc * CH;
  const int basep = base - (cc > 0 ? CH : 0);
  const int tid = threadIdx.x;
  const int lane = tid & 63;
  const int wave = tid >> 6;
  const int quad = lane >> 4, l16 = lane & 15;
  const int m0 = wave * 16;

  __shared__ float Asm[64][64];
  __shared__ float Wsm[64][65];

  floatx4 accA[4] = {};
  floatx4 accP[4] = {};
  floatx4 accM[4] = {};
  floatx4 accN[4] = {};
  const u16* arowK = &Kbf[(size_t)(base + m0 + l16) * 1024];
  const u16* arowQ = &Qbf[(size_t)(base + m0 + l16) * 1024];
#pragma unroll 2
  for (int kk = 0; kk < 32; ++kk) {
    short8 aK = *reinterpret_cast<const short8*>(&arowK[kk * 32 + quad * 8]);
    short8 aQ = *reinterpret_cast<const short8*>(&arowQ[kk * 32 + quad * 8]);
#pragma unroll
    for (int nt = 0; nt < 4; ++nt) {
      short8 bK = *reinterpret_cast<const short8*>(
          &Kbf[(size_t)(base + nt * 16 + l16) * 1024 + kk * 32 + quad * 8]);
      accA[nt] = __builtin_amdgcn_mfma_f32_16x16x32_bf16(aK, bK, accA[nt], 0, 0, 0);
      accP[nt] = __builtin_amdgcn_mfma_f32_16x16x32_bf16(aQ, bK, accP[nt], 0, 0, 0);
    }
    if (cc > 0) {
#pragma unroll
      for (int nt = 0; nt < 4; ++nt) {
        short8 bKp = *reinterpret_cast<const short8*>(
            &Kbf[(size_t)(basep + nt * 16 + l16) * 1024 + kk * 32 + quad * 8]);
        accM[nt] = __builtin_amdgcn_mfma_f32_16x16x32_bf16(aK, bKp, accM[nt], 0, 0, 0);
        accN[nt] = __builtin_amdgcn_mfma_f32_16x16x32_bf16(aQ, bKp, accN[nt], 0, 0, 0);
      }
    }
  }
  const size_t pw0 = ((size_t)(cc * B_ + b) * CH) * 64;
#pragma unroll
  for (int nt = 0; nt < 4; ++nt) {
#pragma unroll
    for (int reg = 0; reg < 4; ++reg) {
      int t = m0 + quad * 4 + reg;
      int i = nt * 16 + l16;
      Asm[t][i] = (i < t) ? accA[nt][reg] : 0.0f;
      Pb[pw0 + (size_t)t * 64 + i] = f2bf((i <= t) ? accP[nt][reg] : 0.0f);
      Mb[pw0 + (size_t)t * 64 + i] = f2bf(accM[nt][reg]);   // zeros when cc==0
      Nb[pw0 + (size_t)t * 64 + i] = f2bf(accN[nt][reg]);
    }
  }
  __syncthreads();

  if (tid < 64) {
    const int j = tid;
    for (int t = 0; t < 64; ++t) {
      float s = (t == j) ? 1.0f : 0.0f;
      for (int i = 0; i < t; ++i) s -= Asm[t][i] * Wsm[i][j];
      Wsm[t][j] = s;
    }
    for (int t = 0; t < 64; ++t)
      Wb[pw0 + (size_t)t * 64 + j] = f2bf(Wsm[t][j]);
  }
}

// ---------------------------------------------------------------------------
// Persistent-state MFMA chain, register-resident fp32 S.
// v4 DIAGNOSIS (v2/v3 post-mortems): two radically different global-load
// schedules (serialized vs 16-deep counted pipeline) both measured ~390us,
// MfmaUtil ~5.5% -- so the cost is the SERIAL recurrence structure: phase A
// (8 latency-exposed LDS->MFMA iterations reading the just-updated Sb) sat
// between u_{cc-1} and u_cc on the barrier-locked path, 32x per launch.
// v4 FIX (chunked delta-rule split): K_{c+1} S_{c+1}^T = K_{c+1} S_c^T +
// (K_{c+1} K_c^T) u_c. The big GEMM (A-early) uses the STALE S -> computed in
// the PREVIOUS chunk's bulk interval against a double-buffered Sb; only the
// 2-MFMA correction (M u) remains on the serial path. Per chunk:
//   i1: corr (2 MFMA) + rhs | bar | i2: u (2 MFMA) | bar |
//   i3: o + phase C + A-early(cc+1) + all prefetch (bulk) | bar
// M/N precomputed in attn_winv (S-independent). Ledger (per i3, both roles):
//   it0 w4 | it1-6 w8 | it7 w4 ; i1 issues af0/af1(next) then w8.
// ---------------------------------------------------------------------------
__global__ __launch_bounds__(512, 2) void chain_kernel(
    const u16* __restrict__ Qbf, const u16* __restrict__ Kbf,
    const u16* __restrict__ KT, const u16* __restrict__ Vbf,
    u16* __restrict__ Obf, const u16* __restrict__ Wb, const u16* __restrict__ Pb,
    const u16* __restrict__ Mb, const u16* __restrict__ Nb,
    float* __restrict__ Sglob, int lsh, int cpg, int g, int ngrp)
{
  const int wg = blockIdx.x;
  // XCD pair {2b, 2b+1} hosts exactly batch b's 64 slices (bijective).
  const int t8 = wg & 7;
  const int b = t8 >> 1;
  const int sl = ((wg >> 3) << 1) | (t8 & 1);
  const int c0 = sl * 16;
  const int tgs = 1 << lsh;
  const int tid = threadIdx.x;
  const int lane = tid & 63;
  const int wave = tid >> 6;
  const int quad = lane >> 4, l16 = lane & 15;
  const int d0w = wave * 128;
  const bool isK = (wave < 4);
  const int m0 = (isK ? wave : (wave - 4)) * 16;
  const size_t ktstep = (size_t)16 * tgs;

  __shared__ u16 Sb[2][16][1048];  // double-buffered bf16 shadow of S
  __shared__ u16 rhsT[16][88];
  __shared__ u16 uT[16][88];

  // Zero uT: prologue corr reads it (M=0 for chunk 0, but garbage LDS could
  // hold NaN patterns and 0*NaN = NaN).
  for (int i = tid; i < 16 * 88 / 2; i += 512)
    reinterpret_cast<unsigned int*>(&uT[0][0])[i] = 0u;

  // fp32 master S: Sreg[nt][reg] <-> S[c=quad*4+reg][d=d0w+nt*16+l16]
  floatx4 Sreg[8];
  if (g == 0) {
#pragma unroll
    for (int nt = 0; nt < 8; ++nt) Sreg[nt] = (floatx4){0.f, 0.f, 0.f, 0.f};
    for (int idx = tid; idx < 16 * 256; idx += 512) {
      int r = idx >> 8, d4 = (idx & 255) * 4;
      ushort4 z4 = {0, 0, 0, 0};
      *reinterpret_cast<ushort4*>(&Sb[0][r][d4]) = z4;
    }
  } else {
#pragma unroll
    for (int nt = 0; nt < 8; ++nt)
#pragma unroll
      for (int reg = 0; reg < 4; ++reg)
        Sreg[nt][reg] = Sglob[((size_t)b * 1024 + c0 + quad * 4 + reg) * 1024 +
                              d0w + nt * 16 + l16];
    for (int idx = tid; idx < 16 * 1024; idx += 512) {
      int r = idx >> 10, d = idx & 1023;
      Sb[0][r][d] = f2bf(Sglob[((size_t)b * 1024 + c0 + r) * 1024 + d]);
    }
  }
  __syncthreads();   // drains vmcnt: ledger starts at 0

  const u16* const Abase  = isK ? Kbf : Qbf;
  const u16* const WPbase = isK ? Wb : Pb;
  const u16* const MNbase = isK ? Mb : Nb;

  short8 af[8][4];
  short8 ktf[8][2];
  short8 wpf0, wpf1, mnf0, mnf1;
  unsigned int vv0, vv1, vv2, vv3;
  floatx4 ac0, ac1, ac2, ac3, accS;

  // ---- prologue: af0/af1 for chunk 0, then A-early(0) + prefetch(0) ----
  {
    const u16* aq0 = Abase + (size_t)(b * tgs + m0 + l16) * 1024 + quad * 8;
    GLA(0, aq0, 0, 64, 128, 192);
    GLA(1, aq0, 256, 320, 384, 448);
  }
  int cur = 0;
  {
    SETPTRS(0);
    const u16* sbRow = &Sb[0][l16][0];
    ac0 = (floatx4){}; ac1 = (floatx4){}; ac2 = (floatx4){}; ac3 = (floatx4){};
    A_IT(0, 4, GLKT(0); GLA(2, aqN, 512, 576, 640, 704););
    A_IT(1, 8, GLKT(2); GLA(3, aqN, 768, 832, 896, 960););
    A_IT(2, 8, GLKT(4); GLA(4, aqN, 1024, 1088, 1152, 1216););
    A_IT(3, 8, GLKT(6); GLA(5, aqN, 1280, 1344, 1408, 1472););
    A_IT(4, 8, GLWM; GLA(6, aqN, 1536, 1600, 1664, 1728););
    A_IT(5, 8, GLA(7, aqN, 1792, 1856, 1920, 1984); GLVV;);
    A_IT(6, 8, NOOP);
    A_IT(7, 4, NOOP);
  }
  I1I2(0);   // corr(M[0]=0) + rhs(0) | bar | u(0) | bar

  for (int cc = 0; cc < cpg; ++cc) {
    const int nx = (cc + 1 < cpg) ? (cc + 1) : (cpg - 1);
    SETPTRS(nx);
    const u16* sbRow = &Sb[cur][l16][0];

    // uT frags (u_cc): used by o, phase C (and fetched fresh for both).
    short8 ua0 = *reinterpret_cast<const short8*>(&uT[l16][quad * 8]);
    short8 ua1 = *reinterpret_cast<const short8*>(&uT[l16][32 + quad * 8]);

    // ---- o = QS + P u (Q-waves). Must precede A_IT4 (wpf reload). ----
    unsigned int s0 = 0, s1 = 0, s2 = 0, s3 = 0;
    u16* ob = nullptr; u16* ob2 = nullptr;
    if (!isK) {
      floatx4 oacc = accS;
      oacc = __builtin_amdgcn_mfma_f32_16x16x32_bf16(wpf0, ua0, oacc, 0, 0, 0);
      oacc = __builtin_amdgcn_mfma_f32_16x16x32_bf16(wpf1, ua1, oacc, 0, 0, 0);
      ob  = Obf + (size_t)(b * tgs + cc * CH + m0 + quad * 4) * 1024 + c0 + l16;
      ob2 = ob + 2048;
      s0 = f2bf(oacc[0]); s1 = f2bf(oacc[1]);
      s2 = f2bf(oacc[2]); s3 = f2bf(oacc[3]);
    }

    // ---- phase C: Sreg += u^T K; writes Sb[cur^1]. Consumes ktf(cc)
    //      BEFORE A_ITs reload those registers for chunk cc+1. ----
    {
#pragma unroll
      for (int nt = 0; nt < 8; ++nt) {
        floatx4 cf = Sreg[nt];
        cf = __builtin_amdgcn_mfma_f32_16x16x32_bf16(ua0, ktf[nt][0], cf, 0, 0, 0);
        cf = __builtin_amdgcn_mfma_f32_16x16x32_bf16(ua1, ktf[nt][1], cf, 0, 0, 0);
        Sreg[nt] = cf;
        const int dn = d0w + nt * 16;
#pragma unroll
        for (int reg = 0; reg < 4; ++reg)
          Sb[cur ^ 1][quad * 4 + reg][dn + l16] = f2bf(cf[reg]);
      }
    }

    // ---- A-early(cc+1): reads STALE Sb[cur]; prefetches chunk cc+1. ----
    ac0 = (floatx4){}; ac1 = (floatx4){}; ac2 = (floatx4){}; ac3 = (floatx4){};
    A_IT(0, 4, GLKT(0); GLA(2, aqN, 512, 576, 640, 704););
    A_IT(1, 8, GLKT(2); GLA(3, aqN, 768, 832, 896, 960););
    A_IT(2, 8, GLKT(4); GLA(4, aqN, 1024, 1088, 1152, 1216););
    A_IT(3, 8, GLKT(6); GLA(5, aqN, 1280, 1344, 1408, 1472););
    A_IT(4, 8, GLWM; GLA(6, aqN, 1536, 1600, 1664, 1728););
    A_IT(5, 8, GLA(7, aqN, 1792, 1856, 1920, 1984); GLVV;);
    A_IT(6, 8, NOOP);
    A_IT(7, 4, NOOP);

    if (!isK) {
      GS(ob, s0, 0);  GS(ob, s1, 2048);
      GS(ob2, s2, 0); GS(ob2, s3, 2048);
    }
    barrier_lgkm();
    cur ^= 1;

    if (cc + 1 < cpg) I1I2(cc + 1);
  }

  asm volatile("s_waitcnt vmcnt(0)");   // retire in-flight asm loads safely

  // spill S for next group (small-ws tiers only; full tier has ngrp==1)
  if (g < ngrp - 1) {
#pragma unroll
    for (int nt = 0; nt < 8; ++nt)
#pragma unroll
      for (int reg = 0; reg < 4; ++reg)
        Sglob[((size_t)b * 1024 + c0 + quad * 4 + reg) * 1024 + d0w + nt * 16 + l16] =
            Sreg[nt][reg];
  }
}

// ---------------------------------------------------------------------------
extern "C" void kernel_launch(void* const* d_in, const int* in_sizes, int n_in,
                              void* d_out, int out_size, void* d_ws, size_t ws_size,
                              hipStream_t stream) {
  const float* x  = (const float*)d_in[0];
  const float* Wq = (const float*)d_in[1];
  const float* Wk = (const float*)d_in[2];
  const float* Wv = (const float*)d_in[3];
  const float* Wo = (const float*)d_in[4];
  float* out = (float*)d_out;

  // tier: largest time-group that fits ws
  int lsh = 8;
  {
    const int cand[4] = {11, 10, 9, 8};
    for (int i = 0; i < 4; ++i) {
      size_t tgs = (size_t)1 << cand[i];
      size_t C = (size_t)B_ * tgs * 1024;
      size_t cpg = tgs / CH;
      size_t need = (size_t)B_ * T_ * 1024 * 2              // Xbf
                  + 4 * ((size_t)1024 * 1024 * 2)           // WT x4
                  + 5 * (C * 2)                             // Qbf,Kbf,Vbf,KT,Obf
                  + 4 * (cpg * B_ * CH * 64 * 2)            // Pb,Wb,Mb,Nb
                  + (size_t)B_ * 1024 * 1024 * 4            // Sglob
                  + 32768;
      if (need <= ws_size) { lsh = cand[i]; break; }
    }
  }
  const int tgs = 1 << lsh;
  const int cpg = tgs / CH;
  const int ngrp = T_ / tgs;
  const int rows = B_ * tgs;

  char* ws = (char*)d_ws;
  size_t off = 0;
  auto alloc = [&](size_t bytes) -> void* {
    void* p = ws + off;
    off += (bytes + 255) & ~(size_t)255;
    return p;
  };
  u16* Xbf = (u16*)alloc((size_t)B_ * T_ * 1024 * 2);
  u16* WqT = (u16*)alloc((size_t)1024 * 1024 * 2);
  u16* WkT = (u16*)alloc((size_t)1024 * 1024 * 2);
  u16* WvT = (u16*)alloc((size_t)1024 * 1024 * 2);
  u16* WoT = (u16*)alloc((size_t)1024 * 1024 * 2);
  u16* Qbf = (u16*)alloc((size_t)rows * 1024 * 2);
  u16* Kbf = (u16*)alloc((size_t)rows * 1024 * 2);
  u16* Vbf = (u16*)alloc((size_t)rows * 1024 * 2);
  u16* KT  = (u16*)alloc((size_t)rows * 1024 * 2);
  u16* Obf = (u16*)alloc((size_t)rows * 1024 * 2);
  u16* Pb  = (u16*)alloc((size_t)cpg * B_ * CH * 64 * 2);
  u16* Wb  = (u16*)alloc((size_t)cpg * B_ * CH * 64 * 2);
  u16* Mb  = (u16*)alloc((size_t)cpg * B_ * CH * 64 * 2);
  u16* Nb  = (u16*)alloc((size_t)cpg * B_ * CH * 64 * 2);
  float* Sglob = (float*)alloc((size_t)B_ * 1024 * 1024 * 4);

  xconv_kernel<<<B_ * T_, 256, 0, stream>>>(x, Xbf);
  wtrans_kernel<<<dim3(16, 16, 4), 256, 0, stream>>>(Wq, Wk, Wv, Wo, WqT, WkT, WvT, WoT);

  for (int g = 0; g < ngrp; ++g) {
    int tg = g * tgs;
    mgemm_qkv<<<dim3(rows / 128, 8, 3), 256, 0, stream>>>(Xbf, WqT, WkT, WvT,
                                                          Qbf, Kbf, Vbf, tg, lsh);
    knorm_kernel<<<rows, 256, 0, stream>>>(Kbf);
    ktrans_kernel<<<dim3(tgs / 64, 16, B_), 256, 0, stream>>>(Kbf, KT, tgs);
    attn_winv_kernel<<<dim3(cpg, B_), 256, 0, stream>>>(Qbf, Kbf, Pb, Wb, Mb, Nb, tgs);
    chain_kernel<<<256, 512, 0, stream>>>(Qbf, Kbf, KT, Vbf, Obf, Wb, Pb, Mb, Nb,
                                          Sglob, lsh, cpg, g, ngrp);
    mgemm_out<<<dim3(rows / 128, 8), 256, 0, stream>>>(Obf, WoT, out, tg, lsh);
  }
}

// Round 8
// 656.981 us; speedup vs baseline: 1.0302x; 1.0302x over previous
//
#include <hip/hip_runtime.h>

typedef unsigned short u16;
typedef __attribute__((ext_vector_type(8))) short short8;     // 8 bf16 (4 VGPRs)
typedef __attribute__((ext_vector_type(4))) float floatx4;    // 4 fp32 acc

#define B_ 4
#define T_ 2048
#define CH 64

__device__ __forceinline__ u16 f2bf(float f) {
  unsigned int x = __float_as_uint(f);
  return (u16)((x + 0x7FFFu + ((x >> 16) & 1u)) >> 16);
}
__device__ __forceinline__ float bf2f(u16 u) {
  union { unsigned int i; float f; } v; v.i = ((unsigned int)u) << 16; return v.f;
}

// lgkm-only barrier: all cross-wave hazards in chain_kernel are LDS.
__device__ __forceinline__ void barrier_lgkm() {
  asm volatile("s_waitcnt lgkmcnt(0)\n\ts_barrier" ::: "memory");
}

// Opaque asm loads: compiler cannot sink/duplicate/rematerialize these, so
// issue points and the hand-counted vmcnt ledger are exact.
#define GL(dst, addr, IMM) \
  asm volatile("global_load_dwordx4 %0, %1, off offset:" #IMM : "=v"(dst) : "v"(addr))
#define GLU(dst, addr, IMM) \
  asm volatile("global_load_ushort %0, %1, off offset:" #IMM : "=v"(dst) : "v"(addr))
#define GS(addr, val, IMM) \
  asm volatile("global_store_short %0, %1, off offset:" #IMM :: "v"(addr), "v"(val))

#define GLA(slot, base, I0, I1, I2, I3) do { \
  GL(af[slot][0], base, I0); GL(af[slot][1], base, I1); \
  GL(af[slot][2], base, I2); GL(af[slot][3], base, I3); } while (0)

#define GLKT(nt0) do { \
  const u16* kp0_ = ktb + (size_t)(nt0) * ktstep; \
  GL(ktf[nt0][0], kp0_, 0); GL(ktf[nt0][1], kp0_, 64); \
  const u16* kp1_ = ktb + (size_t)(nt0 + 1) * ktstep; \
  GL(ktf[nt0 + 1][0], kp1_, 0); GL(ktf[nt0 + 1][1], kp1_, 64); } while (0)

#define GLW do { GL(wpf0, wrow, 0); GL(wpf1, wrow, 64); } while (0)
#define GLVVA do { \
  GLU(vva0, vvba, 0); GLU(vva1, vvba, 2048); \
  GLU(vva2, vvba2, 0); GLU(vva3, vvba2, 2048); } while (0)
#define GLVVB do { \
  GLU(vvb0, vvbb, 0); GLU(vvb1, vvbb, 2048); \
  GLU(vvb2_, vvbb2, 0); GLU(vvb3, vvbb2, 2048); } while (0)

#define NOOP ((void)0);

// One phase-A iteration, TWO c-slices: counted wait (never 0), shared
// prefetch issues, then LDS B-frags for both slices + 8 MFMAs (8 indep
// chains). sched_barrier(0x387) keeps MFMAs below the wait while DS/VALU
// may flow (rule #18: MFMA otherwise hoists past inline-asm waitcnt).
#define A_IT(K, NW, EXTRA) do { \
  asm volatile("s_waitcnt vmcnt(" #NW ")"); \
  __builtin_amdgcn_sched_barrier(0x387); \
  EXTRA \
  short8 pa0_ = *reinterpret_cast<const short8*>(&Sba[l16][(K * 4 + 0) * 32 + quad * 8]); \
  short8 pa1_ = *reinterpret_cast<const short8*>(&Sba[l16][(K * 4 + 1) * 32 + quad * 8]); \
  short8 pa2_ = *reinterpret_cast<const short8*>(&Sba[l16][(K * 4 + 2) * 32 + quad * 8]); \
  short8 pa3_ = *reinterpret_cast<const short8*>(&Sba[l16][(K * 4 + 3) * 32 + quad * 8]); \
  short8 pb0_ = *reinterpret_cast<const short8*>(&Sbb[l16][(K * 4 + 0) * 32 + quad * 8]); \
  short8 pb1_ = *reinterpret_cast<const short8*>(&Sbb[l16][(K * 4 + 1) * 32 + quad * 8]); \
  short8 pb2_ = *reinterpret_cast<const short8*>(&Sbb[l16][(K * 4 + 2) * 32 + quad * 8]); \
  short8 pb3_ = *reinterpret_cast<const short8*>(&Sbb[l16][(K * 4 + 3) * 32 + quad * 8]); \
  ac0a = __builtin_amdgcn_mfma_f32_16x16x32_bf16(af[K][0], pa0_, ac0a, 0, 0, 0); \
  ac0b = __builtin_amdgcn_mfma_f32_16x16x32_bf16(af[K][0], pb0_, ac0b, 0, 0, 0); \
  ac1a = __builtin_amdgcn_mfma_f32_16x16x32_bf16(af[K][1], pa1_, ac1a, 0, 0, 0); \
  ac1b = __builtin_amdgcn_mfma_f32_16x16x32_bf16(af[K][1], pb1_, ac1b, 0, 0, 0); \
  ac2a = __builtin_amdgcn_mfma_f32_16x16x32_bf16(af[K][2], pa2_, ac2a, 0, 0, 0); \
  ac2b = __builtin_amdgcn_mfma_f32_16x16x32_bf16(af[K][2], pb2_, ac2b, 0, 0, 0); \
  ac3a = __builtin_amdgcn_mfma_f32_16x16x32_bf16(af[K][3], pa3_, ac3a, 0, 0, 0); \
  ac3b = __builtin_amdgcn_mfma_f32_16x16x32_bf16(af[K][3], pb3_, ac3b, 0, 0, 0); \
} while (0)

// ---------------------------------------------------------------------------
// x fp32 -> bf16 (full tensor). grid (B_*T_), 256 thr x 4 elems.
// ---------------------------------------------------------------------------
__global__ __launch_bounds__(256) void xconv_kernel(const float* __restrict__ x,
                                                    u16* __restrict__ Xbf) {
  size_t idx = ((size_t)blockIdx.x * 256 + threadIdx.x) * 4;
  float4 v = *reinterpret_cast<const float4*>(&x[idx]);
  ushort4 o;
  o.x = f2bf(v.x); o.y = f2bf(v.y); o.z = f2bf(v.z); o.w = f2bf(v.w);
  *reinterpret_cast<ushort4*>(&Xbf[idx]) = o;
}

// ---------------------------------------------------------------------------
// Weight transpose+convert: T[n][k] = bf16(W[k][n]). grid (16,16,4).
// ---------------------------------------------------------------------------
__global__ __launch_bounds__(256) void wtrans_kernel(
    const float* __restrict__ W0, const float* __restrict__ W1,
    const float* __restrict__ W2, const float* __restrict__ W3,
    u16* __restrict__ T0, u16* __restrict__ T1,
    u16* __restrict__ T2, u16* __restrict__ T3)
{
  const int z = blockIdx.z;
  const float* W = (z == 0) ? W0 : (z == 1) ? W1 : (z == 2) ? W2 : W3;
  u16* T = (z == 0) ? T0 : (z == 1) ? T1 : (z == 2) ? T2 : T3;
  const int k0 = blockIdx.x * 64, n0 = blockIdx.y * 64;
  const int tid = threadIdx.x;
  __shared__ float Tile[64][65];
#pragma unroll
  for (int i = 0; i < 4; ++i) {
    int lin = tid + i * 256;
    int r = lin >> 4, c4 = (lin & 15) * 4;
    *reinterpret_cast<float4*>(&Tile[r][c4]) =
        *reinterpret_cast<const float4*>(&W[(size_t)(k0 + r) * 1024 + n0 + c4]);
  }
  __syncthreads();
#pragma unroll
  for (int i = 0; i < 4; ++i) {
    int lin = tid + i * 256;
    int r = lin >> 4, c4 = (lin & 15) * 4;   // r: n-within, c4: k-within
    ushort4 o;
    o.x = f2bf(Tile[c4 + 0][r]); o.y = f2bf(Tile[c4 + 1][r]);
    o.z = f2bf(Tile[c4 + 2][r]); o.w = f2bf(Tile[c4 + 3][r]);
    *reinterpret_cast<ushort4*>(&T[(size_t)(n0 + r) * 1024 + k0 + c4]) = o;
  }
}

// ---------------------------------------------------------------------------
// MFMA GEMM for QKV. 128x128 tile, 4 waves (2x2), 4x4 of 16x16x32, BK=32.
// grid (rows/128, 8, 3).
// ---------------------------------------------------------------------------
__global__ __launch_bounds__(256) void mgemm_qkv(
    const u16* __restrict__ Xbf,
    const u16* __restrict__ WqT, const u16* __restrict__ WkT, const u16* __restrict__ WvT,
    u16* __restrict__ Qbf, u16* __restrict__ Kbf, u16* __restrict__ Vbf,
    int tg, int lsh)
{
  const int z = blockIdx.z;
  const u16* BT = (z == 0) ? WqT : ((z == 1) ? WkT : WvT);
  u16* O = (z == 0) ? Qbf : ((z == 1) ? Kbf : Vbf);
  const float scale = (z == 0) ? 0.03125f : 1.0f;
  const int r0 = blockIdx.x * 128, c0 = blockIdx.y * 128;
  const int tid = threadIdx.x;
  const int lane = tid & 63, wave = tid >> 6;
  const int quad = lane >> 4, l16 = lane & 15;
  const int wr = (wave >> 1) * 64, wc = (wave & 1) * 64;

  __shared__ u16 As[128][40];
  __shared__ u16 Bs[128][40];

  const int ar = tid >> 1, ac = (tid & 1) * 16;
  const int lr = r0 + ar;
  const int agrow = ((lr >> lsh) << 11) + tg + (lr & ((1 << lsh) - 1));
  const u16* aptr = &Xbf[(size_t)agrow * 1024 + ac];
  const u16* bptr = &BT[(size_t)(c0 + ar) * 1024 + ac];

  floatx4 acc[4][4] = {};
  for (int k0 = 0; k0 < 1024; k0 += 32) {
    float4 av0 = *reinterpret_cast<const float4*>(aptr + k0);
    float4 av1 = *reinterpret_cast<const float4*>(aptr + k0 + 8);
    float4 bv0 = *reinterpret_cast<const float4*>(bptr + k0);
    float4 bv1 = *reinterpret_cast<const float4*>(bptr + k0 + 8);
    __syncthreads();
    *reinterpret_cast<float4*>(&As[ar][ac]) = av0;
    *reinterpret_cast<float4*>(&As[ar][ac + 8]) = av1;
    *reinterpret_cast<float4*>(&Bs[ar][ac]) = bv0;
    *reinterpret_cast<float4*>(&Bs[ar][ac + 8]) = bv1;
    __syncthreads();
    short8 afr[4], bfr[4];
#pragma unroll
    for (int i = 0; i < 4; ++i) {
      afr[i] = *reinterpret_cast<const short8*>(&As[wr + i * 16 + l16][quad * 8]);
      bfr[i] = *reinterpret_cast<const short8*>(&Bs[wc + i * 16 + l16][quad * 8]);
    }
#pragma unroll
    for (int mi = 0; mi < 4; ++mi)
#pragma unroll
      for (int ni = 0; ni < 4; ++ni)
        acc[mi][ni] = __builtin_amdgcn_mfma_f32_16x16x32_bf16(afr[mi], bfr[ni], acc[mi][ni], 0, 0, 0);
  }
#pragma unroll
  for (int mi = 0; mi < 4; ++mi)
#pragma unroll
    for (int reg = 0; reg < 4; ++reg) {
      int row = r0 + wr + mi * 16 + quad * 4 + reg;
#pragma unroll
      for (int ni = 0; ni < 4; ++ni) {
        int col = c0 + wc + ni * 16 + l16;
        O[(size_t)row * 1024 + col] = f2bf(acc[mi][ni][reg] * scale);
      }
    }
}

// ---------------------------------------------------------------------------
// MFMA GEMM out-proj: fp32 out. grid (rows/128, 8)
// ---------------------------------------------------------------------------
__global__ __launch_bounds__(256) void mgemm_out(
    const u16* __restrict__ Obf, const u16* __restrict__ WoT,
    float* __restrict__ out, int tg, int lsh)
{
  const int r0 = blockIdx.x * 128, c0 = blockIdx.y * 128;
  const int tid = threadIdx.x;
  const int lane = tid & 63, wave = tid >> 6;
  const int quad = lane >> 4, l16 = lane & 15;
  const int wr = (wave >> 1) * 64, wc = (wave & 1) * 64;

  __shared__ u16 As[128][40];
  __shared__ u16 Bs[128][40];

  const int ar = tid >> 1, ac = (tid & 1) * 16;
  const u16* aptr = &Obf[(size_t)(r0 + ar) * 1024 + ac];
  const u16* bptr = &WoT[(size_t)(c0 + ar) * 1024 + ac];

  floatx4 acc[4][4] = {};
  for (int k0 = 0; k0 < 1024; k0 += 32) {
    float4 av0 = *reinterpret_cast<const float4*>(aptr + k0);
    float4 av1 = *reinterpret_cast<const float4*>(aptr + k0 + 8);
    float4 bv0 = *reinterpret_cast<const float4*>(bptr + k0);
    float4 bv1 = *reinterpret_cast<const float4*>(bptr + k0 + 8);
    __syncthreads();
    *reinterpret_cast<float4*>(&As[ar][ac]) = av0;
    *reinterpret_cast<float4*>(&As[ar][ac + 8]) = av1;
    *reinterpret_cast<float4*>(&Bs[ar][ac]) = bv0;
    *reinterpret_cast<float4*>(&Bs[ar][ac + 8]) = bv1;
    __syncthreads();
    short8 afr[4], bfr[4];
#pragma unroll
    for (int i = 0; i < 4; ++i) {
      afr[i] = *reinterpret_cast<const short8*>(&As[wr + i * 16 + l16][quad * 8]);
      bfr[i] = *reinterpret_cast<const short8*>(&Bs[wc + i * 16 + l16][quad * 8]);
    }
#pragma unroll
    for (int mi = 0; mi < 4; ++mi)
#pragma unroll
      for (int ni = 0; ni < 4; ++ni)
        acc[mi][ni] = __builtin_amdgcn_mfma_f32_16x16x32_bf16(afr[mi], bfr[ni], acc[mi][ni], 0, 0, 0);
  }
#pragma unroll
  for (int mi = 0; mi < 4; ++mi)
#pragma unroll
    for (int reg = 0; reg < 4; ++reg) {
      int lr = r0 + wr + mi * 16 + quad * 4 + reg;
      int grow = ((lr >> lsh) << 11) + tg + (lr & ((1 << lsh) - 1));
#pragma unroll
      for (int ni = 0; ni < 4; ++ni) {
        int col = c0 + wc + ni * 16 + l16;
        out[(size_t)grow * 1024 + col] = acc[mi][ni][reg];
      }
    }
}

// ---------------------------------------------------------------------------
// Row-normalize Kbf in place (bf16, fp32 math). grid (rows).
// ---------------------------------------------------------------------------
__global__ __launch_bounds__(256) void knorm_kernel(u16* __restrict__ Kbf) {
  const int row = blockIdx.x;
  const int tid = threadIdx.x;
  ushort4 v4 = *reinterpret_cast<const ushort4*>(&Kbf[(size_t)row * 1024 + tid * 4]);
  float a = bf2f(v4.x), b = bf2f(v4.y), c = bf2f(v4.z), d = bf2f(v4.w);
  float ss = a * a + b * b + c * c + d * d;
#pragma unroll
  for (int off = 32; off > 0; off >>= 1) ss += __shfl_down(ss, off);
  __shared__ float wsum[4];
  if ((tid & 63) == 0) wsum[tid >> 6] = ss;
  __syncthreads();
  float tot = wsum[0] + wsum[1] + wsum[2] + wsum[3];
  float inv = 1.0f / fmaxf(sqrtf(tot), 1e-12f);
  ushort4 o;
  o.x = f2bf(a * inv); o.y = f2bf(b * inv); o.z = f2bf(c * inv); o.w = f2bf(d * inv);
  *reinterpret_cast<ushort4*>(&Kbf[(size_t)row * 1024 + tid * 4]) = o;
}

// ---------------------------------------------------------------------------
// Transpose Kbf -> KT[b][d][t_local] (bf16). grid (tgs/64, 16, B_), 256 thr.
// ---------------------------------------------------------------------------
__global__ __launch_bounds__(256) void ktrans_kernel(const u16* __restrict__ Kbf,
                                                     u16* __restrict__ KT,
                                                     int tgs) {
  const int t0 = blockIdx.x * 64;
  const int d0 = blockIdx.y * 64;
  const int b = blockIdx.z;
  const int tid = threadIdx.x;
  __shared__ u16 Tile[64][68];
#pragma unroll
  for (int i = 0; i < 4; ++i) {
    int lin = tid + i * 256;
    int r = lin >> 4, c4 = (lin & 15) * 4;
    *reinterpret_cast<ushort4*>(&Tile[r][c4]) =
        *reinterpret_cast<const ushort4*>(&Kbf[(size_t)(b * tgs + t0 + r) * 1024 + d0 + c4]);
  }
  __syncthreads();
#pragma unroll
  for (int i = 0; i < 4; ++i) {
    int lin = tid + i * 256;
    int r = lin >> 4, c4 = (lin & 15) * 4;
    ushort4 o;
    o.x = Tile[c4 + 0][r]; o.y = Tile[c4 + 1][r];
    o.z = Tile[c4 + 2][r]; o.w = Tile[c4 + 3][r];
    *reinterpret_cast<ushort4*>(&KT[((size_t)b * 1024 + d0 + r) * tgs + t0 + c4]) = o;
  }
}

// ---------------------------------------------------------------------------
// Per (chunk, batch): MFMA QK^T/KK^T -> P and A -> W=(I+A)^{-1} -> bf16.
// grid (cpg, B_), 256 threads.
// ---------------------------------------------------------------------------
__global__ __launch_bounds__(256) void attn_winv_kernel(
    const u16* __restrict__ Qbf, const u16* __restrict__ Kbf,
    u16* __restrict__ Pb, u16* __restrict__ Wb, int tgs)
{
  const int cc = blockIdx.x;
  const int b = blockIdx.y;
  const int base = b * tgs + cc * CH;
  const int tid = threadIdx.x;
  const int lane = tid & 63;
  const int wave = tid >> 6;
  const int quad = lane >> 4, l16 = lane & 15;
  const int m0 = wave * 16;

  __shared__ float Asm[64][64];
  __shared__ float Wsm[64][65];

  floatx4 accA[4] = {};
  floatx4 accP[4] = {};
  const u16* arowK = &Kbf[(size_t)(base + m0 + l16) * 1024];
  const u16* arowQ = &Qbf[(size_t)(base + m0 + l16) * 1024];
#pragma unroll 4
  for (int kk = 0; kk < 32; ++kk) {
    short8 aK = *reinterpret_cast<const short8*>(&arowK[kk * 32 + quad * 8]);
    short8 aQ = *reinterpret_cast<const short8*>(&arowQ[kk * 32 + quad * 8]);
#pragma unroll
    for (int nt = 0; nt < 4; ++nt) {
      short8 bK = *reinterpret_cast<const short8*>(
          &Kbf[(size_t)(base + nt * 16 + l16) * 1024 + kk * 32 + quad * 8]);
      accA[nt] = __builtin_amdgcn_mfma_f32_16x16x32_bf16(aK, bK, accA[nt], 0, 0, 0);
      accP[nt] = __builtin_amdgcn_mfma_f32_16x16x32_bf16(aQ, bK, accP[nt], 0, 0, 0);
    }
  }
  const size_t pw0 = ((size_t)(cc * B_ + b) * CH) * 64;
#pragma unroll
  for (int nt = 0; nt < 4; ++nt) {
#pragma unroll
    for (int reg = 0; reg < 4; ++reg) {
      int t = m0 + quad * 4 + reg;
      int i = nt * 16 + l16;
      Asm[t][i] = (i < t) ? accA[nt][reg] : 0.0f;
      Pb[pw0 + (size_t)t * 64 + i] = f2bf((i <= t) ? accP[nt][reg] : 0.0f);
    }
  }
  __syncthreads();

  if (tid < 64) {
    const int j = tid;
    for (int t = 0; t < 64; ++t) {
      float s = (t == j) ? 1.0f : 0.0f;
      for (int i = 0; i < t; ++i) s -= Asm[t][i] * Wsm[i][j];
      Wsm[t][j] = s;
    }
    for (int t = 0; t < 64; ++t)
      Wb[pw0 + (size_t)t * 64 + j] = f2bf(Wsm[t][j]);
  }
}

// ---------------------------------------------------------------------------
// Persistent-state MFMA chain, v5: TWO c-slices per WG.
// DIAGNOSIS (v1-v4): 4 radically different schedules all ~390-430us with
// MfmaUtil pinned at 5.4% -> not latency-schedule-bound. The invariant is
// per-WG per-chunk traffic: each of 256 WGs (c-width 16) re-reads the FULL
// K/Q/KT chunk (~390KB, ~6.5k lines) -> 64x cross-WG read amplification.
// v5 LEVER: two c-slices (sl, sl+32) share K/Q/KT/W/P entirely -- same load
// count per chunk, but TWO recurrences advance. 128 WGs (XCD-bijective).
// Discriminates: latency-bound -> ~0.6x time; VMEM-throughput-bound -> flat.
// vmcnt ledger (both roles; Q-stores issue after g15, only strengthen waits):
//   A_IT waits: 4,8,12,12,12,10,14,12 ; end wait 8 ; entry outstanding = 8.
// ---------------------------------------------------------------------------
__global__ __launch_bounds__(512, 2) void chain_kernel(
    const u16* __restrict__ Qbf, const u16* __restrict__ Kbf,
    const u16* __restrict__ KT, const u16* __restrict__ Vbf,
    u16* __restrict__ Obf, const u16* __restrict__ Wb, const u16* __restrict__ Pb,
    float* __restrict__ Sglob, int lsh, int cpg, int g, int ngrp)
{
  const int wg = blockIdx.x;   // 128 WGs
  // XCD pair {2b,2b+1} hosts batch b (bijective for nwg=128, 8 XCDs).
  const int t8 = wg & 7;
  const int b = t8 >> 1;
  const int slp = ((wg >> 3) << 1) | (t8 & 1);   // 0..31 slice-pair id
  const int c0a = slp * 16;
  const int c0b = c0a + 512;                     // slice slp+32
  const int tgs = 1 << lsh;
  const int tid = threadIdx.x;
  const int lane = tid & 63;
  const int wave = tid >> 6;
  const int quad = lane >> 4, l16 = lane & 15;
  const int d0w = wave * 128;
  const bool isK = (wave < 4);
  const int m0 = (isK ? wave : (wave - 4)) * 16;
  const size_t ktstep = (size_t)16 * tgs;

  __shared__ u16 Sba[16][1048];   // bf16 shadow of S, slice a
  __shared__ u16 Sbb[16][1048];   // slice b
  __shared__ u16 rhsTa[16][88];
  __shared__ u16 rhsTb[16][88];
  __shared__ u16 uTa[16][88];
  __shared__ u16 uTb[16][88];

  // fp32 master S: Sreg*[nt][reg] <-> S[c=quad*4+reg][d=d0w+nt*16+l16]
  floatx4 SregA[8], SregB[8];
  if (g == 0) {
#pragma unroll
    for (int nt = 0; nt < 8; ++nt) {
      SregA[nt] = (floatx4){0.f, 0.f, 0.f, 0.f};
      SregB[nt] = (floatx4){0.f, 0.f, 0.f, 0.f};
    }
    for (int idx = tid; idx < 16 * 256; idx += 512) {
      int r = idx >> 8, d4 = (idx & 255) * 4;
      ushort4 z4 = {0, 0, 0, 0};
      *reinterpret_cast<ushort4*>(&Sba[r][d4]) = z4;
      *reinterpret_cast<ushort4*>(&Sbb[r][d4]) = z4;
    }
  } else {
#pragma unroll
    for (int nt = 0; nt < 8; ++nt)
#pragma unroll
      for (int reg = 0; reg < 4; ++reg) {
        SregA[nt][reg] = Sglob[((size_t)b * 1024 + c0a + quad * 4 + reg) * 1024 +
                               d0w + nt * 16 + l16];
        SregB[nt][reg] = Sglob[((size_t)b * 1024 + c0b + quad * 4 + reg) * 1024 +
                               d0w + nt * 16 + l16];
      }
    for (int idx = tid; idx < 16 * 1024; idx += 512) {
      int r = idx >> 10, d = idx & 1023;
      Sba[r][d] = f2bf(Sglob[((size_t)b * 1024 + c0a + r) * 1024 + d]);
      Sbb[r][d] = f2bf(Sglob[((size_t)b * 1024 + c0b + r) * 1024 + d]);
    }
  }
  __syncthreads();   // drains vmcnt: ledger starts at 0

  const u16* const Abase  = isK ? Kbf : Qbf;
  const u16* const WPbase = isK ? Wb : Pb;

  short8 af[8][4];    // shared A-frag ring (K rows for K-waves, Q for Q-waves)
  short8 ktf[8][2];   // shared KT frags
  short8 wpf0, wpf1;  // shared W (K-waves) / P (Q-waves) row frags
  unsigned int vva0, vva1, vva2, vva3;
  unsigned int vvb0, vvb1, vvb2_, vvb3;

  const u16* arow = Abase + (size_t)(b * tgs + m0 + l16) * 1024;  // chunk 0

  // Prologue: chunk 0, iter 0/1 A-frags (8 loads -> matches steady entry).
  {
    const u16* aq0 = arow + quad * 8;
    GLA(0, aq0, 0, 64, 128, 192);
    GLA(1, aq0, 256, 320, 384, 448);
  }

  for (int cc = 0; cc < cpg; ++cc) {
    const int base = b * tgs + cc * CH;
    const size_t pw0 = ((size_t)(cc * B_ + b) * CH) * 64;

    const u16* aq   = arow + quad * 8;
    const u16* aqn  = arow + (size_t)(cc + 1 < cpg ? CH * 1024 : 0) + quad * 8;
    const u16* ktb  = KT + ((size_t)b * 1024 + d0w + l16) * tgs + (size_t)cc * CH + quad * 8;
    const u16* wrow = WPbase + pw0 + (size_t)(m0 + l16) * 64 + quad * 8;
    const u16* vvba  = Vbf + (size_t)(base + m0 + quad * 4) * 1024 + c0a + l16;
    const u16* vvba2 = vvba + 2048;
    const u16* vvbb  = Vbf + (size_t)(base + m0 + quad * 4) * 1024 + c0b + l16;
    const u16* vvbb2 = vvbb + 2048;

    floatx4 ac0a = {}, ac1a = {}, ac2a = {}, ac3a = {};
    floatx4 ac0b = {}, ac1b = {}, ac2b = {}, ac3b = {};

    // Issue groups (ledger): g1=GLA2 g2=GLKT0 | g3=GLA3 g4=GLKT2 | g5=GLA4
    // g6=GLKT4 | g7=GLA5 g8=GLKT6 | g9=GLA6 g10=GLW | g11=GLA7 g12=GLVVA
    // g13=GLVVB | g14=GLA0' | g15=GLA1'
    A_IT(0, 4,  GLA(2, aq, 512, 576, 640, 704);     GLKT(0););
    A_IT(1, 8,  GLA(3, aq, 768, 832, 896, 960);     GLKT(2););
    A_IT(2, 12, GLA(4, aq, 1024, 1088, 1152, 1216); GLKT(4););
    A_IT(3, 12, GLA(5, aq, 1280, 1344, 1408, 1472); GLKT(6););
    A_IT(4, 12, GLA(6, aq, 1536, 1600, 1664, 1728); GLW;);
    A_IT(5, 10, GLA(7, aq, 1792, 1856, 1920, 1984); GLVVA; GLVVB;);
    A_IT(6, 14, GLA(0, aqn, 0, 64, 128, 192););
    A_IT(7, 12, GLA(1, aqn, 256, 320, 384, 448););

    // Covers vv (g12,g13), wpf (g10), ktf (g2..g8): only g14,g15 younger.
    asm volatile("s_waitcnt vmcnt(8)");
    __builtin_amdgcn_sched_barrier(0);

    floatx4 accSa = (ac0a + ac1a) + (ac2a + ac3a);
    floatx4 accSb = (ac0b + ac1b) + (ac2b + ac3b);

    // ---- rhs = V - KS (K-waves), both slices ----
    if (isK) {
      rhsTa[l16][m0 + quad * 4 + 0] = f2bf(bf2f((u16)vva0) - accSa[0]);
      rhsTa[l16][m0 + quad * 4 + 1] = f2bf(bf2f((u16)vva1) - accSa[1]);
      rhsTa[l16][m0 + quad * 4 + 2] = f2bf(bf2f((u16)vva2) - accSa[2]);
      rhsTa[l16][m0 + quad * 4 + 3] = f2bf(bf2f((u16)vva3) - accSa[3]);
      rhsTb[l16][m0 + quad * 4 + 0] = f2bf(bf2f((u16)vvb0) - accSb[0]);
      rhsTb[l16][m0 + quad * 4 + 1] = f2bf(bf2f((u16)vvb1) - accSb[1]);
      rhsTb[l16][m0 + quad * 4 + 2] = f2bf(bf2f((u16)vvb2_) - accSb[2]);
      rhsTb[l16][m0 + quad * 4 + 3] = f2bf(bf2f((u16)vvb3) - accSb[3]);
    }
    barrier_lgkm();

    // ---- u = W * rhs (K-waves), both slices ----
    if (isK) {
      floatx4 uaccA = {}, uaccB = {};
      short8 bra0 = *reinterpret_cast<const short8*>(&rhsTa[l16][quad * 8]);
      short8 bra1 = *reinterpret_cast<const short8*>(&rhsTa[l16][32 + quad * 8]);
      short8 brb0 = *reinterpret_cast<const short8*>(&rhsTb[l16][quad * 8]);
      short8 brb1 = *reinterpret_cast<const short8*>(&rhsTb[l16][32 + quad * 8]);
      uaccA = __builtin_amdgcn_mfma_f32_16x16x32_bf16(wpf0, bra0, uaccA, 0, 0, 0);
      uaccA = __builtin_amdgcn_mfma_f32_16x16x32_bf16(wpf1, bra1, uaccA, 0, 0, 0);
      uaccB = __builtin_amdgcn_mfma_f32_16x16x32_bf16(wpf0, brb0, uaccB, 0, 0, 0);
      uaccB = __builtin_amdgcn_mfma_f32_16x16x32_bf16(wpf1, brb1, uaccB, 0, 0, 0);
#pragma unroll
      for (int reg = 0; reg < 4; ++reg) {
        uTa[l16][m0 + quad * 4 + reg] = f2bf(uaccA[reg]);
        uTb[l16][m0 + quad * 4 + reg] = f2bf(uaccB[reg]);
      }
    }
    barrier_lgkm();

    // ---- u frags (all waves) ----
    short8 ua0a = *reinterpret_cast<const short8*>(&uTa[l16][quad * 8]);
    short8 ua1a = *reinterpret_cast<const short8*>(&uTa[l16][32 + quad * 8]);
    short8 ua0b = *reinterpret_cast<const short8*>(&uTb[l16][quad * 8]);
    short8 ua1b = *reinterpret_cast<const short8*>(&uTb[l16][32 + quad * 8]);

    // ---- o = QS + P*u (Q-waves), both slices; asm stores (after all loads) --
    if (!isK) {
      floatx4 oaccA = accSa, oaccB = accSb;
      oaccA = __builtin_amdgcn_mfma_f32_16x16x32_bf16(wpf0, ua0a, oaccA, 0, 0, 0);
      oaccA = __builtin_amdgcn_mfma_f32_16x16x32_bf16(wpf1, ua1a, oaccA, 0, 0, 0);
      oaccB = __builtin_amdgcn_mfma_f32_16x16x32_bf16(wpf0, ua0b, oaccB, 0, 0, 0);
      oaccB = __builtin_amdgcn_mfma_f32_16x16x32_bf16(wpf1, ua1b, oaccB, 0, 0, 0);
      u16* oba  = Obf + (size_t)(base + m0 + quad * 4) * 1024 + c0a + l16;
      u16* oba2 = oba + 2048;
      u16* obb  = Obf + (size_t)(base + m0 + quad * 4) * 1024 + c0b + l16;
      u16* obb2 = obb + 2048;
      unsigned int sa0 = f2bf(oaccA[0]), sa1 = f2bf(oaccA[1]);
      unsigned int sa2 = f2bf(oaccA[2]), sa3 = f2bf(oaccA[3]);
      unsigned int sb0 = f2bf(oaccB[0]), sb1 = f2bf(oaccB[1]);
      unsigned int sb2 = f2bf(oaccB[2]), sb3 = f2bf(oaccB[3]);
      GS(oba, sa0, 0);  GS(oba, sa1, 2048);
      GS(oba2, sa2, 0); GS(oba2, sa3, 2048);
      GS(obb, sb0, 0);  GS(obb, sb1, 2048);
      GS(obb2, sb2, 0); GS(obb2, sb3, 2048);
    }

    // ---- phase C: Sreg += u^T K (shared ktf), both slices ----
    {
#pragma unroll
      for (int nt = 0; nt < 8; ++nt) {
        floatx4 ca = SregA[nt];
        ca = __builtin_amdgcn_mfma_f32_16x16x32_bf16(ua0a, ktf[nt][0], ca, 0, 0, 0);
        ca = __builtin_amdgcn_mfma_f32_16x16x32_bf16(ua1a, ktf[nt][1], ca, 0, 0, 0);
        SregA[nt] = ca;
        floatx4 cb = SregB[nt];
        cb = __builtin_amdgcn_mfma_f32_16x16x32_bf16(ua0b, ktf[nt][0], cb, 0, 0, 0);
        cb = __builtin_amdgcn_mfma_f32_16x16x32_bf16(ua1b, ktf[nt][1], cb, 0, 0, 0);
        SregB[nt] = cb;
        const int dn = d0w + nt * 16;
#pragma unroll
        for (int reg = 0; reg < 4; ++reg) {
          Sba[quad * 4 + reg][dn + l16] = f2bf(ca[reg]);
          Sbb[quad * 4 + reg][dn + l16] = f2bf(cb[reg]);
        }
      }
    }
    barrier_lgkm();
    arow += CH * 1024;
  }

  asm volatile("s_waitcnt vmcnt(0)");   // retire in-flight asm loads safely

  // spill S for next group (small-ws tiers only; full tier has ngrp==1)
  if (g < ngrp - 1) {
#pragma unroll
    for (int nt = 0; nt < 8; ++nt)
#pragma unroll
      for (int reg = 0; reg < 4; ++reg) {
        Sglob[((size_t)b * 1024 + c0a + quad * 4 + reg) * 1024 + d0w + nt * 16 + l16] =
            SregA[nt][reg];
        Sglob[((size_t)b * 1024 + c0b + quad * 4 + reg) * 1024 + d0w + nt * 16 + l16] =
            SregB[nt][reg];
      }
  }
}

// ---------------------------------------------------------------------------
extern "C" void kernel_launch(void* const* d_in, const int* in_sizes, int n_in,
                              void* d_out, int out_size, void* d_ws, size_t ws_size,
                              hipStream_t stream) {
  const float* x  = (const float*)d_in[0];
  const float* Wq = (const float*)d_in[1];
  const float* Wk = (const float*)d_in[2];
  const float* Wv = (const float*)d_in[3];
  const float* Wo = (const float*)d_in[4];
  float* out = (float*)d_out;

  // tier: largest time-group that fits ws
  int lsh = 8;
  {
    const int cand[4] = {11, 10, 9, 8};
    for (int i = 0; i < 4; ++i) {
      size_t tgs = (size_t)1 << cand[i];
      size_t C = (size_t)B_ * tgs * 1024;
      size_t cpg = tgs / CH;
      size_t need = (size_t)B_ * T_ * 1024 * 2              // Xbf
                  + 4 * ((size_t)1024 * 1024 * 2)           // WT x4
                  + 5 * (C * 2)                             // Qbf,Kbf,Vbf,KT,Obf
                  + 2 * (cpg * B_ * CH * 64 * 2)            // Pb,Wb
                  + (size_t)B_ * 1024 * 1024 * 4            // Sglob
                  + 32768;
      if (need <= ws_size) { lsh = cand[i]; break; }
    }
  }
  const int tgs = 1 << lsh;
  const int cpg = tgs / CH;
  const int ngrp = T_ / tgs;
  const int rows = B_ * tgs;

  char* ws = (char*)d_ws;
  size_t off = 0;
  auto alloc = [&](size_t bytes) -> void* {
    void* p = ws + off;
    off += (bytes + 255) & ~(size_t)255;
    return p;
  };
  u16* Xbf = (u16*)alloc((size_t)B_ * T_ * 1024 * 2);
  u16* WqT = (u16*)alloc((size_t)1024 * 1024 * 2);
  u16* WkT = (u16*)alloc((size_t)1024 * 1024 * 2);
  u16* WvT = (u16*)alloc((size_t)1024 * 1024 * 2);
  u16* WoT = (u16*)alloc((size_t)1024 * 1024 * 2);
  u16* Qbf = (u16*)alloc((size_t)rows * 1024 * 2);
  u16* Kbf = (u16*)alloc((size_t)rows * 1024 * 2);
  u16* Vbf = (u16*)alloc((size_t)rows * 1024 * 2);
  u16* KT  = (u16*)alloc((size_t)rows * 1024 * 2);
  u16* Obf = (u16*)alloc((size_t)rows * 1024 * 2);
  u16* Pb  = (u16*)alloc((size_t)cpg * B_ * CH * 64 * 2);
  u16* Wb  = (u16*)alloc((size_t)cpg * B_ * CH * 64 * 2);
  float* Sglob = (float*)alloc((size_t)B_ * 1024 * 1024 * 4);

  xconv_kernel<<<B_ * T_, 256, 0, stream>>>(x, Xbf);
  wtrans_kernel<<<dim3(16, 16, 4), 256, 0, stream>>>(Wq, Wk, Wv, Wo, WqT, WkT, WvT, WoT);

  for (int g = 0; g < ngrp; ++g) {
    int tg = g * tgs;
    mgemm_qkv<<<dim3(rows / 128, 8, 3), 256, 0, stream>>>(Xbf, WqT, WkT, WvT,
                                                          Qbf, Kbf, Vbf, tg, lsh);
    knorm_kernel<<<rows, 256, 0, stream>>>(Kbf);
    ktrans_kernel<<<dim3(tgs / 64, 16, B_), 256, 0, stream>>>(Kbf, KT, tgs);
    attn_winv_kernel<<<dim3(cpg, B_), 256, 0, stream>>>(Qbf, Kbf, Pb, Wb, tgs);
    chain_kernel<<<128, 512, 0, stream>>>(Qbf, Kbf, KT, Vbf, Obf, Wb, Pb, Sglob,
                                          lsh, cpg, g, ngrp);
    mgemm_out<<<dim3(rows / 128, 8), 256, 0, stream>>>(Obf, WoT, out, tg, lsh);
  }
}